// Round 13
// baseline (126.820 us; speedup 1.0000x reference)
//
#include <hip/hip_runtime.h>
#include <hip/hip_bf16.h>

// 1-NN VQ via split-bf16 MFMA + exact fp32 refinement.
//   score[q][k] = csq[k] - 2*dot(q,c_k); out = argmin_k (lowest-k tie-break).
// Phase 0 (knn_prep): codebook -> bf16 hi/lo fragment-ready cbB (kb-major) + csq.
// Phase A (knn_mfma): persistent codebook, 4 waves/SIMD n-split (r22).
//   Ladder: r16 1w/SIMD=51.5 | r17/r21 2w lockstep=39-41 (r21: +A-prefetch,
//   MfmaUtil 23%, total 120.2) | r18 +barriers=53 | r19 3w 170-cap=69 (acc
//   demoted to scratch) | r20 bundle=58-64 (antiphase x setprio starvation).
//   r21 accounting: 24.6k cyc/batch vs ~12-13k of dep-chain content -> two
//   LOCKSTEP waves ~= 2x serialized; dependency-latency-bound, no pipe >25%.
//   TLP is the proven lever; LDS-bytes irrelevant (r18); barriers poison.
//   r22: TLP=4 below the reg cliff: 1024 thr / 16 waves / 4 per SIMD
//   (launch_bounds(1024,4) -> 128-reg cap). Wave pairs {2p,2p+1} split the
//   16 n-tiles: m=1, t=8 -> acc[8]=32 AGPR (r19's cliff was a 64-reg acc at
//   170 cap; half the array, more slack: arch ~105 <= 128). No A-prefetch
//   (TLP covers it). Cross-half merge moved OFF-KERNEL: waves write partial
//   {bf,sf,bi} (3 MB ws), new memory-bound knn_merge kernel does the union +
//   gap<T flagging -> knn_mfma keeps ZERO steady-state barriers.
//   Structure: whole split codebook (128 KB) in LDS once (8x gload_lds
//   w=16/wave); ONE barrier (bt==0); 4 batches x 16 q/pair-wave; K-loop pure
//   ds_read_b128+MFMA over this half's 8 n-tiles; dot ~= qh.ch+ql.ch+qh.cl
//   (err ~1.9e-3); float top-2 per half.
// Phase M (knn_merge): per q, union of 2 half-top-2s; out + gap<T worklist.
// Phase B (knn_refine): exact fp32 rescan (u64 keys, lowest-k tie-break).
// Tripwires: knn_mfma WRITE_SIZE >> 5 MB (3.5 expected) or VGPR=128+scratch
//   => 128-cap spill => fall back to r21.

typedef __bf16 bf16x8 __attribute__((ext_vector_type(8)));
typedef float  floatx4 __attribute__((ext_vector_type(4)));

#define MFMA16 __builtin_amdgcn_mfma_f32_16x16x32_bf16

#define CNT_OFF 0
#define CSQ_OFF 1024
#define CBB_OFF 4096
#define WL_OFF  (4096 + 131072)                  // 135168, 128 KB worklist
#define PBF_OFF (WL_OFF + WL_CAP * 4)            // 266240, float2[262144] = 2 MB
#define PBI_OFF (PBF_OFF + 2097152)              // 2363392, int[262144] = 1 MB
#define WL_CAP  32768
#define T_FLAG  0.004f

typedef __attribute__((address_space(1))) const unsigned int gu32;
typedef __attribute__((address_space(3))) unsigned int lu32;

__device__ __forceinline__ unsigned fmap(float f) {
    unsigned u = __float_as_uint(f);
    return (u & 0x80000000u) ? ~u : (u | 0x80000000u);
}

// ---------------- Phase 0: codebook split, kb-major fragment layout, csq ----------------
// cbB element index = ((kb*16 + t)*2 + part)*512 + ln*8 + j   (= id*8 below)
//   kb = k-chunk 0..3; t = ntile 0..15; part: 0=hi 1=lo;
//   lane ln: n = t*16 + (ln&15), k = kb*32 + (ln>>4)*8 + j.
__global__ void knn_prep(const float* __restrict__ cb, __bf16* __restrict__ cbB,
                         float* __restrict__ csq, int* __restrict__ cnt) {
    const int tid = threadIdx.x;
    const int id = blockIdx.x * 256 + tid;       // 0..8191
    if (id == 0) *cnt = 0;
    const int ln = id & 63;
    const int part = (id >> 6) & 1;
    const int step = id >> 7;                    // kb*16 + t
    const int t4 = step & 15;
    const int kb = step >> 4;
    const int n = t4 * 16 + (ln & 15);
    const int k0 = kb * 32 + (ln >> 4) * 8;
    const float* src = cb + (size_t)n * 128 + k0;
    union { __bf16 h[8]; uint4 u; } p;
#pragma unroll
    for (int j = 0; j < 8; ++j) {
        float f = src[j];
        __bf16 hh = (__bf16)f;
        p.h[j] = (part == 0) ? hh : (__bf16)(f - (float)hh);
    }
    *(uint4*)(cbB + (size_t)id * 8) = p.u;

    if (blockIdx.x == 0) {
        const float4* row = (const float4*)(cb + (size_t)tid * 128);
        float a0 = 0.f, a1 = 0.f, a2 = 0.f, a3 = 0.f;
#pragma unroll 8
        for (int j = 0; j < 32; ++j) {
            float4 v = row[j];
            a0 = fmaf(v.x, v.x, a0);
            a1 = fmaf(v.y, v.y, a1);
            a2 = fmaf(v.z, v.z, a2);
            a3 = fmaf(v.w, v.w, a3);
        }
        csq[tid] = (a0 + a1) + (a2 + a3);
    }
}

// ---------------- Phase A: persistent-codebook MFMA, half-top-2 partials ----------------
__global__ __launch_bounds__(1024, 4) void knn_mfma(const float* __restrict__ x,
                                                    const __bf16* __restrict__ cbB,
                                                    const float* __restrict__ csq_g,
                                                    float2* __restrict__ pbf,
                                                    int* __restrict__ pbi) {
    __shared__ __bf16 sB[65536];                 // 128 KB: ENTIRE split codebook

    const int tid = threadIdx.x;
    const int wave = tid >> 6;                   // 0..15 (4 waves/SIMD)
    const int lane = tid & 63;
    const int rl = lane & 15;                    // n col within tile
    const int kg = lane >> 4;                    // q-row group 0..3
    const int pair = wave >> 1;                  // 0..7
    const int half = wave & 1;                   // n-half: t = half*8 + tt

    // ---- one-time B fill: wave w copies 8 KB (8 x 1 KB, linear) ----
    {
        const char* gsrc = (const char*)cbB + wave * 8192 + lane * 16;
        char* ldst = (char*)sB + wave * 8192;
#pragma unroll
        for (int i = 0; i < 8; ++i)
            __builtin_amdgcn_global_load_lds((gu32*)(gsrc + i * 1024),
                                             (lu32*)(ldst + i * 1024), 16, 0, 0);
    }

    float cs[8];
#pragma unroll
    for (int tt = 0; tt < 8; ++tt) cs[tt] = csq_g[(half * 8 + tt) * 16 + rl];

    // ---- 4 batches of 16 q per pair (both half-waves same A) ----
#pragma unroll 1
    for (int bt = 0; bt < 4; ++bt) {
        const size_t q0 = (size_t)blockIdx.x * 512 + bt * 128 + pair * 16;

        // ---- A: load + split-convert this pair's m-tile into registers ----
        const float* xq = x + (q0 + rl) * 128 + kg * 8;
        bf16x8 ah[4], al[4];
#pragma unroll
        for (int kb = 0; kb < 4; ++kb) {
            float4 f0 = *(const float4*)(xq + kb * 32);
            float4 f1 = *(const float4*)(xq + kb * 32 + 4);
            float f[8] = {f0.x, f0.y, f0.z, f0.w, f1.x, f1.y, f1.z, f1.w};
            union { __bf16 h[8]; bf16x8 v; } phv, plv;
#pragma unroll
            for (int j = 0; j < 8; ++j) {
                __bf16 hh = (__bf16)f[j];
                phv.h[j] = hh;
                plv.h[j] = (__bf16)(f[j] - (float)hh);
            }
            ah[kb] = phv.v;
            al[kb] = plv.v;
        }

        floatx4 acc[8];
#pragma unroll
        for (int tt = 0; tt < 8; ++tt) acc[tt] = (floatx4){0.f, 0.f, 0.f, 0.f};

        if (bt == 0) __syncthreads();            // B fill landed (vmcnt drain), once

        // ---- K-loop: this half's 8 n-tiles, pure LDS reads + MFMA ----
        // element offset = kb*16384 + (half*8+tt)*1024 + part*512 + lane*8
#pragma unroll
        for (int kb = 0; kb < 4; ++kb) {
            const __bf16* sbase = sB + kb * 16384 + half * 8192 + lane * 8;
#pragma unroll
            for (int tt = 0; tt < 8; ++tt) {
                bf16x8 bh = *(const bf16x8*)(sbase + tt * 1024);
                bf16x8 bl = *(const bf16x8*)(sbase + tt * 1024 + 512);
                acc[tt] = MFMA16(ah[kb], bh, acc[tt], 0, 0, 0);
                acc[tt] = MFMA16(al[kb], bh, acc[tt], 0, 0, 0);
                acc[tt] = MFMA16(ah[kb], bl, acc[tt], 0, 0, 0);
            }
        }

        // ---- epilogue: float-domain top-2 over this half's 128 codes ----
#pragma unroll
        for (int r = 0; r < 4; ++r) {
            float bf = __builtin_inff(), sf = __builtin_inff();
            int bi = 0;
#pragma unroll
            for (int tt = 0; tt < 8; ++tt) {
                const float sc = fmaf(-2.0f, acc[tt][r], cs[tt]);
                const bool lt = sc < bf;
                sf = lt ? bf : fminf(sf, sc);
                bf = lt ? sc : bf;
                bi = lt ? ((half * 8 + tt) * 16 + rl) : bi;
            }
#pragma unroll
            for (int d = 1; d < 16; d <<= 1) {
                const float obf = __shfl_xor(bf, d);
                const int   obi = __shfl_xor(bi, d);
                const float osf = __shfl_xor(sf, d);
                const bool lt = obf < bf;
                const float loser = lt ? bf : obf;           // larger best
                sf = fminf(fminf(sf, osf), loser);
                bf = lt ? obf : bf;
                bi = lt ? obi : bi;
            }
            if (rl == 0) {
                const size_t qg = q0 + kg * 4 + r;
                pbf[qg * 2 + half] = (float2){bf, sf};
                pbi[qg * 2 + half] = bi;
            }
        }
    }
}

// ---------------- Phase M: merge the two half-top-2s per query ----------------
__global__ __launch_bounds__(256) void knn_merge(const float2* __restrict__ pbf,
                                                 const int* __restrict__ pbi,
                                                 int* __restrict__ out,
                                                 int* __restrict__ cnt,
                                                 int* __restrict__ wl) {
    const int q = blockIdx.x * 256 + threadIdx.x;
    // halves adjacent: 16B {b0,s0,b1,s1} + 8B {i0,i1}, fully coalesced
    const float4 v = *(const float4*)(pbf + (size_t)q * 2);
    const int2  iv = *(const int2*)(pbi + (size_t)q * 2);
    const bool w0 = v.x < v.z;
    const float B = w0 ? v.x : v.z;
    const float S = fminf(w0 ? v.y : v.w, w0 ? v.z : v.x);
    out[q] = w0 ? iv.x : iv.y;
    if (S - B < T_FLAG) {                        // small gap or tie -> exact pass
        int idx = atomicAdd(cnt, 1);
        if (idx < WL_CAP) wl[idx] = q;
    }
}

// ---------------- Phase B: exact fp32 rescan, block-per-query ----------------
__global__ __launch_bounds__(256) void knn_refine(const float* __restrict__ x,
                                                  const float* __restrict__ cb,
                                                  const float* __restrict__ csq_g,
                                                  const int* __restrict__ wl,
                                                  const int* __restrict__ cnt,
                                                  int* __restrict__ out) {
    __shared__ unsigned long long sP[4];
    const int tid = threadIdx.x;           // == code index k
    const int lane = tid & 63;
    const int wave = tid >> 6;

    int n = *cnt;
    if (n > WL_CAP) n = WL_CAP;
    const float mycsq = csq_g[tid];
    const float4* cr = (const float4*)(cb + (size_t)tid * 128);

    for (int i = blockIdx.x; i < n; i += gridDim.x) {
        const int q = wl[i];
        const float4* qr = (const float4*)(x + (size_t)q * 128);
        float a0 = 0.f, a1 = 0.f, a2 = 0.f, a3 = 0.f;
#pragma unroll 8
        for (int c4 = 0; c4 < 32; ++c4) {
            float4 qv = qr[c4];            // broadcast (same addr all lanes)
            float4 cv = cr[c4];
            a0 = fmaf(qv.x, cv.x, a0);
            a1 = fmaf(qv.y, cv.y, a1);
            a2 = fmaf(qv.z, cv.z, a2);
            a3 = fmaf(qv.w, cv.w, a3);
        }
        float dot = (a0 + a1) + (a2 + a3);
        float score = fmaf(-2.0f, dot, mycsq);
        unsigned long long key =
            ((unsigned long long)fmap(score) << 32) | (unsigned)tid;
#pragma unroll
        for (int d = 1; d < 64; d <<= 1) {
            unsigned long long o = __shfl_xor(key, d);
            key = o < key ? o : key;
        }
        if (lane == 0) sP[wave] = key;
        __syncthreads();
        if (tid == 0) {
            unsigned long long b = sP[0];
            unsigned long long o;
            o = sP[1]; b = o < b ? o : b;
            o = sP[2]; b = o < b ? o : b;
            o = sP[3]; b = o < b ? o : b;
            out[q] = (int)(unsigned)(b & 0xFFFFFFFFull);
        }
        __syncthreads();
    }
}

extern "C" void kernel_launch(void* const* d_in, const int* in_sizes, int n_in,
                              void* d_out, int out_size, void* d_ws, size_t ws_size,
                              hipStream_t stream) {
    const float* x = (const float*)d_in[0];
    const float* cb = (const float*)d_in[1];
    int* out = (int*)d_out;

    char* ws = (char*)d_ws;
    int* cnt = (int*)(ws + CNT_OFF);
    float* csq = (float*)(ws + CSQ_OFF);
    __bf16* cbB = (__bf16*)(ws + CBB_OFF);
    int* wl = (int*)(ws + WL_OFF);
    float2* pbf = (float2*)(ws + PBF_OFF);
    int* pbi = (int*)(ws + PBI_OFF);

    const int M = in_sizes[0] / 128;     // 131072

    knn_prep<<<32, 256, 0, stream>>>(cb, cbB, csq, cnt);
    knn_mfma<<<M / 512, 1024, 0, stream>>>(x, cbB, csq, pbf, pbi);
    knn_merge<<<M / 256, 256, 0, stream>>>(pbf, pbi, out, cnt, wl);
    knn_refine<<<240, 256, 0, stream>>>(x, cb, csq, wl, cnt, out);
}